// Round 12
// baseline (1044.398 us; speedup 1.0000x reference)
//
#include <hip/hip_runtime.h>
#include <cstdint>
#include <cstddef>
#include <type_traits>

// ---------------- problem constants ----------------
#define OUT_DIM    65
#define TREE_STRIDE 66
#define N_NODE     1023
#define N_INTN     511

typedef _Float16 f16;
typedef _Float16 f16x8 __attribute__((ext_vector_type(8)));
typedef _Float16 f16x4 __attribute__((ext_vector_type(4)));
typedef float    f32x4 __attribute__((ext_vector_type(4)));

template<int V> using ic = std::integral_constant<int, V>;

#define MFMA(a, b, c) __builtin_amdgcn_mfma_f32_16x16x32_f16((a), (b), (c), 0, 0, 0)

// counted wait, compile-time immediates; "memory" clobber pins load scheduling.
template<int VM, int LG>
__device__ __forceinline__ void waitcnt_t() {
  asm volatile("s_waitcnt vmcnt(%0) lgkmcnt(%1)" :: "n"(VM), "n"(LG) : "memory");
}

// H swizzle: elem(row,k) at row*512 + (((k>>3) ^ (row&15))<<3) + (k&7)
template<int MT>
__device__ __forceinline__ void storeH_fn(f16* __restrict__ H, f32x4 (&acc)[MT][4],
                                          const float* __restrict__ bias,
                                          int wcb, int quad, int l16) {
#pragma unroll
  for (int mt = 0; mt < MT; mt++) {
#pragma unroll
    for (int nt = 0; nt < 4; nt++) {
      const int c0 = wcb + nt * 16 + quad * 4;
      const float4 bv = *(const float4*)(bias + c0);
      f16x4 hv;
      float v0 = acc[mt][nt][0] + bv.x; hv[0] = (f16)(v0 > 0.f ? v0 : 0.f);
      float v1 = acc[mt][nt][1] + bv.y; hv[1] = (f16)(v1 > 0.f ? v1 : 0.f);
      float v2 = acc[mt][nt][2] + bv.z; hv[2] = (f16)(v2 > 0.f ? v2 : 0.f);
      float v3 = acc[mt][nt][3] + bv.w; hv[3] = (f16)(v3 > 0.f ? v3 : 0.f);
      const int row = mt * 16 + l16;
      *(f16x4*)&H[row * 512 + (((c0 >> 3) ^ l16) << 3) + (quad & 1) * 4] = hv;
    }
  }
}

// ---------------------------------------------------------------------------
// Barrier-free K-loop (round-8 proven). B: global->VGPR from FRAGMENT-LINEAR
// weights (coalesced 1KB dwordx4). A: via GetA (ds_read or global). BD/AD
// rings, counted waits, no __syncthreads inside.
// REGISTER REGIME (rounds 4-11): occupancy buckets at total(arch+acc)
// 64/128/256 per wave. MT=4: ~184 total -> 2 waves/SIMD, no spill (rounds
// 6/8). MT=8 (acc 128) and MT=2-under-(512,4) both spill. DO NOT move tile
// size or launch bounds again.
// ---------------------------------------------------------------------------
template<int NC, int MT, int NT, int BD, int AD, bool AGLOB, bool SWAP,
         typename GetB, typename GetA>
__device__ __forceinline__ void kloop(GetB getB, GetA getA, f32x4 (&acc)[MT][NT])
{
  f16x8 bs[BD][NT];
  f16x8 as[AD][MT];
#pragma unroll
  for (int c = 0; c < BD - 1 && c < NC; c++)
#pragma unroll
    for (int nt = 0; nt < NT; nt++) bs[c][nt] = getB(c, nt);
#pragma unroll
  for (int c = 0; c < AD - 1 && c < NC; c++)
#pragma unroll
    for (int mt = 0; mt < MT; mt++) as[c][mt] = getA(c, mt);

  auto lp = [&](auto&& self, auto Cc) -> void {
    constexpr int C = decltype(Cc)::value;
    if constexpr (C < NC) {
      if constexpr (C + BD - 1 < NC) {
#pragma unroll
        for (int nt = 0; nt < NT; nt++) bs[(C + BD - 1) % BD][nt] = getB(C + BD - 1, nt);
      }
      if constexpr (C + AD - 1 < NC) {
#pragma unroll
        for (int mt = 0; mt < MT; mt++) as[(C + AD - 1) % AD][mt] = getA(C + AD - 1, mt);
      }
      constexpr int BOUT = (BD - 1) < (NC - 1 - C) ? (BD - 1) : (NC - 1 - C);
      constexpr int AOUT = (AD - 1) < (NC - 1 - C) ? (AD - 1) : (NC - 1 - C);
      if constexpr (AGLOB) waitcnt_t<0, 0>();       // A-globals share vmcnt
      else                 waitcnt_t<NT * BOUT, MT * AOUT>();
      __builtin_amdgcn_s_setprio(1);
#pragma unroll
      for (int mt = 0; mt < MT; mt++)
#pragma unroll
        for (int nt = 0; nt < NT; nt++)
          acc[mt][nt] = SWAP ? MFMA(bs[C % BD][nt], as[C % AD][mt], acc[mt][nt])
                             : MFMA(as[C % AD][mt], bs[C % BD][nt], acc[mt][nt]);
      __builtin_amdgcn_s_setprio(0);
      self(self, ic<C + 1>{});
    }
  };
  lp(lp, ic<0>{});
}

// one 512-col layer, MT*16 rows, 8 waves each owning 64 cols.
// B fragment-linear: frag(c, cb, lane) at ((c*32 + cb)*64 + lane)*8 f16,
// cb = wave*4 + nt.
template<int K, int MT, bool AGLOB, typename GetA>
__device__ __forceinline__ void run_layer(
    const f16* __restrict__ Wt, const float* __restrict__ bias,
    f16* __restrict__ H, int wave, int lane, int quad, int l16, GetA getA)
{
  constexpr int NC = K / 32;
  const int wcb = wave * 64;
  const f16* bbase = Wt + (long)(wave * 4) * 512 + lane * 8;
  auto getB = [&](int c, int nt) -> f16x8 {
    return *(const f16x8*)(bbase + (long)(c * 32 + nt) * 512);
  };
  f32x4 acc[MT][4];
#pragma unroll
  for (int i = 0; i < MT; i++)
#pragma unroll
    for (int j = 0; j < 4; j++) acc[i][j] = f32x4{0.f, 0.f, 0.f, 0.f};

  kloop<NC, MT, 4, 4, 2, AGLOB, true>(getB, getA, acc);  // swapped: row=l16, col=quad*4+r

  __syncthreads();                 // all H/X reads of this layer done
  storeH_fn<MT>(H, acc, bias, wcb, quad, l16);
  __syncthreads();                 // H visible for next layer
}

// ---------------- fused 4-layer MLP, 64 rows/block, 512 thr (round 8) -------
// LDS: H[64][512] = 64KB. X[64][232] (internal l0 input) aliases H — safe:
// storeH(l0) writes H only after the barrier when all X reads are done.
__global__ __launch_bounds__(512, 2) void fused_mlp(
    const float* __restrict__ feats,
    const f16* __restrict__ w0t, const float* __restrict__ b0,
    const f16* __restrict__ w1t, const float* __restrict__ b1,
    const f16* __restrict__ w2t, const float* __restrict__ b2,
    const f16* __restrict__ wot, const float* __restrict__ bo,
    f16* __restrict__ tree, float* __restrict__ dOut, int lvl, int leaf)
{
  extern __shared__ f16 S[];
  f16* H = S;            // 32768 f16
  f16* X = S;            // [64][232] (internal l0 only; alias of H)

  const int tid  = threadIdx.x;
  const int wave = tid >> 6;
  const int lane = tid & 63;
  const int quad = lane >> 4;
  const int l16  = lane & 15;
  const long rowBase = (long)blockIdx.x * 64;

  if (!leaf) {
    // feats: 64 rows x 64, f32->f16, coalesced
    for (int i = tid; i < 4096; i += 512) {
      int r = i >> 6, cc = i & 63;
      long rg = rowBase + r;
      long bbr = rg >> lvl;
      long ii = rg - (bbr << lvl);
      long nn = (1L << lvl) - 1 + ii;
      X[r * 232 + cc] = (f16)feats[(bbr * N_INTN + nn) * 64 + cc];
    }
    // children: 64 rows x 132 f16 VERBATIM copy (66 u32/row, contiguous).
    // Junk cols (col65 of each child) land at k=129,195: weight rows there
    // are ZERO (hole repack + K bound), and tree col65 is zeroed by every
    // epilogue, so junk is finite -> 0*finite = 0.
    for (int i = tid; i < 4224; i += 512) {
      int r = i / 66, c = i - r * 66;
      long rg = rowBase + r;
      long bbr = rg >> lvl;
      long ii = rg - (bbr << lvl);
      long nn = (1L << lvl) - 1 + ii;
      const uint32_t* src = (const uint32_t*)(tree + (bbr * N_NODE + 2 * nn + 1) * TREE_STRIDE);
      *(uint32_t*)(X + r * 232 + 64 + 2 * c) = src[c];
    }
    // zero k=196..223 (read range ends at 223; avoid NaN*0)
    for (int i = tid; i < 1792; i += 512) {
      int r = i / 28, cc = i - r * 28;
      X[r * 232 + 196 + cc] = (f16)0.f;
    }
    __syncthreads();
  }

  // ---- layer 0 ----
  if (leaf) {
    auto gA = [&](int c, int mt) -> f16x8 {
      const float4* p = (const float4*)(feats + (rowBase + mt * 16 + l16) * 64 + c * 32 + quad * 8);
      float4 u0 = p[0], u1 = p[1];
      f16x8 a;
      a[0] = (f16)u0.x; a[1] = (f16)u0.y; a[2] = (f16)u0.z; a[3] = (f16)u0.w;
      a[4] = (f16)u1.x; a[5] = (f16)u1.y; a[6] = (f16)u1.z; a[7] = (f16)u1.w;
      return a;
    };
    run_layer<64, 4, true>(w0t, b0, H, wave, lane, quad, l16, gA);
  } else {
    auto gA = [&](int c, int mt) -> f16x8 {
      int row = mt * 16 + l16;
      return *(const f16x8*)&X[row * 232 + c * 32 + quad * 8];  // max 223 < 232
    };
    run_layer<224, 4, false>(w0t, b0, H, wave, lane, quad, l16, gA);
  }

  // ---- mid layers (A from H) ----
  auto getAH = [&](int c, int mt) -> f16x8 {
    int row = mt * 16 + l16;
    return *(const f16x8*)&H[row * 512 + ((((c * 4 + quad) ^ l16) << 3))];
  };
  run_layer<512, 4, false>(w1t, b1, H, wave, lane, quad, l16, getAH);
  run_layer<512, 4, false>(w2t, b2, H, wave, lane, quad, l16, getAH);

  // ---- out layer (512 -> 65), waves 0..3 compute 16 rows each ----
  if (wave < 4) {
    const f16* obase = wot + lane * 8;             // frag-linear, NB=5
    auto gB = [&](int c, int nt) -> f16x8 {
      return *(const f16x8*)(obase + (long)(c * 5 + nt) * 512);
    };
    const int orow = wave * 16 + l16;
    auto gA = [&](int c, int mt) -> f16x8 {
      return *(const f16x8*)&H[orow * 512 + ((((c * 4 + quad) ^ l16) << 3))];
    };
    f32x4 oacc[1][5];
#pragma unroll
    for (int i = 0; i < 5; i++) oacc[0][i] = f32x4{0.f, 0.f, 0.f, 0.f};

    kloop<16, 1, 5, 3, 2, false, false>(gB, gA, oacc);  // normal: row=quad*4+r, col=nt*16+l16

#pragma unroll
    for (int nt = 0; nt < 5; nt++)
#pragma unroll
      for (int r = 0; r < 4; r++) {
        int col = nt * 16 + l16;
        long rg = rowBase + wave * 16 + quad * 4 + r;
        long b2_ = rg >> lvl;
        long ii  = rg - (b2_ << lvl);
        long node = (1L << lvl) - 1 + ii;
        if (col < OUT_DIM) {
          float v = oacc[0][nt][r] + bo[col];
          tree[(b2_ * N_NODE + node) * TREE_STRIDE + col] = (f16)v;
          if (lvl == 0 && col == 0) dOut[rg] = v;
        } else if (col == OUT_DIM) {
          tree[(b2_ * N_NODE + node) * TREE_STRIDE + col] = (f16)0.f;
        }
      }
  }
}

// ---------------- tail: levels 5..0 IN-BLOCK, one batch element per block ---
// Child outputs never touch global: LDS double-buffer prev/cur [32][66].
// Level 5 reads level-6 children from tree (written by the l6 dispatch).
// Same barrier-free frag-linear structure as fused_mlp, MT=2 (32-row tile,
// rows >= M are clamped duplicates, writes guarded by row < M).
// LDS: H[32][512] 32KB (X[32][232] aliases) + childA/childB 2x2112 f16.
__global__ __launch_bounds__(512, 2) void tail_mlp(
    const float* __restrict__ feats,
    const f16* __restrict__ w0t, const float* __restrict__ b0,
    const f16* __restrict__ w1t, const float* __restrict__ b1,
    const f16* __restrict__ w2t, const float* __restrict__ b2,
    const f16* __restrict__ wot, const float* __restrict__ bo,
    const f16* __restrict__ tree, float* __restrict__ dOut)
{
  extern __shared__ f16 S[];
  f16* H = S;              // 16384 f16 = 32KB
  f16* X = S;              // [32][232] alias of H
  f16* childA = S + 16384; // 2112 f16
  f16* childB = S + 18496; // 2112 f16  -> total 20608 f16 = 41216 B

  const long b   = blockIdx.x;
  const int tid  = threadIdx.x;
  const int wave = tid >> 6;
  const int lane = tid & 63;
  const int quad = lane >> 4;
  const int l16  = lane & 15;

  f16* prev = childA;
  f16* cur  = childB;

  auto getAH = [&](int c, int mt) -> f16x8 {
    int row = mt * 16 + l16;
    return *(const f16x8*)&H[row * 512 + ((((c * 4 + quad) ^ l16) << 3))];
  };
  auto gAX = [&](int c, int mt) -> f16x8 {
    int row = mt * 16 + l16;
    return *(const f16x8*)&X[row * 232 + c * 32 + quad * 8];
  };

  for (int l = 5; l >= 0; --l) {
    const int M = 1 << l;

    // ---- stage X[32][232]: 16 threads/row; rows >= M clamp to M-1 (the
    //      duplicate writes store identical values -> benign) ----
    {
      const int r  = tid >> 4;         // 0..31
      const int p  = tid & 15;
      const int rr = r < M ? r : M - 1;
      const long nn = (long)(M - 1) + rr;
      const float* fsrc = feats + (b * N_INTN + nn) * 64 + p * 4;
      f16* xr = X + r * 232;
      float4 v = *(const float4*)fsrc;
      f16x4 h; h[0] = (f16)v.x; h[1] = (f16)v.y; h[2] = (f16)v.z; h[3] = (f16)v.w;
      *(f16x4*)(xr + p * 4) = h;
      // children: 132 f16 verbatim (66 u32). l=5: from tree (l6 output,
      // col65 zeroed there). l<5: from prev LDS buffer rows 2rr,2rr+1
      // (contiguous, col65 zeroed by our epilogue).
      const uint32_t* csrc = (l == 5)
          ? (const uint32_t*)(tree + (b * N_NODE + 2 * nn + 1) * TREE_STRIDE)
          : (const uint32_t*)(prev + 2 * rr * 66);
      uint32_t* xd = (uint32_t*)(xr + 64);
#pragma unroll
      for (int j = 0; j < 5; j++) {
        int c = p * 5 + j;
        if (c < 66) xd[c] = csrc[c];
      }
#pragma unroll
      for (int j = 0; j < 2; j++) {    // zero k=196..223
        int z = p * 2 + j;
        if (z < 28) xr[196 + z] = (f16)0.f;
      }
      __syncthreads();
    }

    // ---- 4 layers (MT=2: 32 rows) ----
    run_layer<224, 2, false>(w0t, b0, H, wave, lane, quad, l16, gAX);
    run_layer<512, 2, false>(w1t, b1, H, wave, lane, quad, l16, getAH);
    run_layer<512, 2, false>(w2t, b2, H, wave, lane, quad, l16, getAH);

    // ---- out layer: waves 0..1 (32 rows), NB=5, write cur LDS ----
    if (wave < 2) {
      const f16* obase = wot + lane * 8;
      auto gB = [&](int c, int nt) -> f16x8 {
        return *(const f16x8*)(obase + (long)(c * 5 + nt) * 512);
      };
      const int orow = wave * 16 + l16;
      auto gA = [&](int c, int mt) -> f16x8 {
        return *(const f16x8*)&H[orow * 512 + ((((c * 4 + quad) ^ l16) << 3))];
      };
      f32x4 oacc[1][5];
#pragma unroll
      for (int i = 0; i < 5; i++) oacc[0][i] = f32x4{0.f, 0.f, 0.f, 0.f};

      kloop<16, 1, 5, 3, 2, false, false>(gB, gA, oacc);

      const int rowb = wave * 16 + quad * 4;
#pragma unroll
      for (int nt = 0; nt < 5; nt++)
#pragma unroll
        for (int r = 0; r < 4; r++) {
          int col = nt * 16 + l16;
          int row = rowb + r;
          if (row < M) {
            if (col < OUT_DIM) {
              float v = oacc[0][nt][r] + bo[col];
              cur[row * 66 + col] = (f16)v;
              if (l == 0 && col == 0 && row == 0) dOut[b] = v;
            } else if (col == OUT_DIM) {
              cur[row * 66 + col] = (f16)0.f;   // pad col read by verbatim copy
            }
          }
        }
    }
    __syncthreads();     // cur complete; H free for next level's X staging
    f16* t = prev; prev = cur; cur = t;
  }
}

// ---------------- weight repack: transpose+cast to FRAGMENT-LINEAR ----------
// elem e of a segment: j=e&7, lane=(e>>3)&63, q=e>>9, cb=q%NB, c=q/NB;
// stores W[k= c*32+(lane>>4)*8+j][col= cb*16+(lane&15)] (0-padded).
// hole: logical row `hole` is a ZERO row and source rows shift by 1 above it.
struct WSeg { const float* W; f16* Wt; int K, N, NB, hole, start; };
struct WPack { WSeg s[8]; int total; };

__global__ void wcast_all(WPack p) {
  int idx = blockIdx.x * 256 + threadIdx.x;
  if (idx >= p.total) return;
  int si = 0;
#pragma unroll
  for (int i = 1; i < 8; i++) if (idx >= p.s[i].start) si = i;
  WSeg sg = p.s[si];
  int e = idx - sg.start;
  int j = e & 7, lane = (e >> 3) & 63, q = e >> 9;
  int cb = q % sg.NB, c = q / sg.NB;
  int col = cb * 16 + (lane & 15);
  int k = c * 32 + (lane >> 4) * 8 + j;
  int srck = (k < sg.hole) ? k : k - 1;
  float v = (k != sg.hole && srck < sg.K && col < sg.N)
                ? sg.W[(long)srck * sg.N + col] : 0.f;
  sg.Wt[e] = (f16)v;
}

// ---------------- host orchestration ----------------
extern "C" void kernel_launch(void* const* d_in, const int* in_sizes, int n_in,
                              void* d_out, int out_size, void* d_ws, size_t ws_size,
                              hipStream_t stream) {
  const float* leaf_feats     = (const float*)d_in[0];
  const float* internal_feats = (const float*)d_in[1];
  const float* lw0 = (const float*)d_in[2];
  const float* lb0 = (const float*)d_in[3];
  const float* lw1 = (const float*)d_in[4];
  const float* lb1 = (const float*)d_in[5];
  const float* lw2 = (const float*)d_in[6];
  const float* lb2 = (const float*)d_in[7];
  const float* lwo = (const float*)d_in[8];
  const float* lbo = (const float*)d_in[9];
  const float* iw0 = (const float*)d_in[10];
  const float* ib0 = (const float*)d_in[11];
  const float* iw1 = (const float*)d_in[12];
  const float* ib1 = (const float*)d_in[13];
  const float* iw2 = (const float*)d_in[14];
  const float* ib2 = (const float*)d_in[15];
  const float* iwo = (const float*)d_in[16];
  const float* ibo = (const float*)d_in[17];
  float* dOut = (float*)d_out;

  char* ws = (char*)d_ws;
  size_t off = 0;
  auto alloc = [&](size_t bytes) -> void* {
    void* p = ws + off;
    off += (bytes + 255) & ~(size_t)255;
    return p;
  };

  f16* lw0t = (f16*)alloc((size_t)64  * 512 * 2);
  f16* lw1t = (f16*)alloc((size_t)512 * 512 * 2);
  f16* lw2t = (f16*)alloc((size_t)512 * 512 * 2);
  f16* lwot = (f16*)alloc((size_t)512 * 80  * 2);
  f16* iw0t = (f16*)alloc((size_t)224 * 512 * 2);
  f16* iw1t = (f16*)alloc((size_t)512 * 512 * 2);
  f16* iw2t = (f16*)alloc((size_t)512 * 512 * 2);
  f16* iwot = (f16*)alloc((size_t)512 * 80  * 2);
  f16* tree = (f16*)alloc((size_t)256 * N_NODE * TREE_STRIDE * 2);

  const int NOHOLE = 1 << 30;
  WPack p;
  int cum = 0;
  auto seg = [&](int i, const float* W, f16* Wt, int K, int N, int Kpad, int NB, int hole) {
    p.s[i] = {W, Wt, K, N, NB, hole, cum};
    cum += Kpad * NB * 16;
  };
  seg(0, lw0, lw0t, 64, 512, 64, 32, NOHOLE);
  seg(1, lw1, lw1t, 512, 512, 512, 32, NOHOLE);
  seg(2, lw2, lw2t, 512, 512, 512, 32, NOHOLE);
  seg(3, lwo, lwot, 512, 65, 512, 5, NOHOLE);
  seg(4, iw0, iw0t, 194, 512, 224, 32, 129);   // hole at k=129 (left child pad)
  seg(5, iw1, iw1t, 512, 512, 512, 32, NOHOLE);
  seg(6, iw2, iw2t, 512, 512, 512, 32, NOHOLE);
  seg(7, iwo, iwot, 512, 65, 512, 5, NOHOLE);
  p.total = cum;
  wcast_all<<<dim3((cum + 255) / 256), dim3(256), 0, stream>>>(p);

  static bool attrSet = false;
  if (!attrSet) {
    hipFuncSetAttribute(reinterpret_cast<const void*>(fused_mlp),
                        hipFuncAttributeMaxDynamicSharedMemorySize, 65536);
    hipFuncSetAttribute(reinterpret_cast<const void*>(tail_mlp),
                        hipFuncAttributeMaxDynamicSharedMemorySize, 41216);
    attrSet = true;
  }

  const size_t shmem     = 65536;   // fused: H 64KB (X aliased)
  const size_t tailShmem = 41216;   // tail: H 32KB + 2x child 4224B

  // leaf pass: 131072 rows -> nodes 511..1022
  fused_mlp<<<dim3(2048), dim3(512), shmem, stream>>>(
      leaf_feats, lw0t, lb0, lw1t, lb1, lw2t, lb2, lwot, lbo, tree, dOut, 9, 1);

  // big internal levels 8..6 (grid = rows/64 = 4<<l)
  for (int l = 8; l >= 6; l--) {
    fused_mlp<<<dim3(4u << l), dim3(512), shmem, stream>>>(
        internal_feats, iw0t, ib0, iw1t, ib1, iw2t, ib2, iwot, ibo, tree, dOut, l, 0);
  }

  // levels 5..0 in ONE dispatch: one block per batch element, children in LDS
  tail_mlp<<<dim3(256), dim3(512), tailShmem, stream>>>(
      internal_feats, iw0t, ib0, iw1t, ib1, iw2t, ib2, iwot, ibo, tree, dOut);

  (void)in_sizes; (void)n_in; (void)out_size; (void)ws_size;
}

// Round 14
// 632.991 us; speedup vs baseline: 1.6499x; 1.6499x over previous
//
#include <hip/hip_runtime.h>
#include <cstdint>
#include <cstddef>
#include <type_traits>

// ---------------- problem constants ----------------
#define OUT_DIM    65
#define TREE_STRIDE 66
#define N_NODE     1023
#define N_INTN     511

typedef _Float16 f16;
typedef _Float16 f16x8 __attribute__((ext_vector_type(8)));
typedef _Float16 f16x4 __attribute__((ext_vector_type(4)));
typedef float    f32x4 __attribute__((ext_vector_type(4)));

template<int V> using ic = std::integral_constant<int, V>;

#define MFMA(a, b, c) __builtin_amdgcn_mfma_f32_16x16x32_f16((a), (b), (c), 0, 0, 0)

// counted wait, compile-time immediates; "memory" clobber pins load scheduling.
// Correctness never relies on these (compiler emits its own waits before each
// use of a loaded value); they only ADD earlier/looser waits for scheduling.
template<int VM, int LG>
__device__ __forceinline__ void waitcnt_t() {
  asm volatile("s_waitcnt vmcnt(%0) lgkmcnt(%1)" :: "n"(VM), "n"(LG) : "memory");
}

// H swizzle: elem(row,k) at row*512 + (((k>>3) ^ (row&15))<<3) + (k&7)
template<int MT>
__device__ __forceinline__ void storeH_fn(f16* __restrict__ H, f32x4 (&acc)[MT][4],
                                          const float* __restrict__ bias,
                                          int wcb, int quad, int l16) {
#pragma unroll
  for (int mt = 0; mt < MT; mt++) {
#pragma unroll
    for (int nt = 0; nt < 4; nt++) {
      const int c0 = wcb + nt * 16 + quad * 4;
      const float4 bv = *(const float4*)(bias + c0);
      f16x4 hv;
      float v0 = acc[mt][nt][0] + bv.x; hv[0] = (f16)(v0 > 0.f ? v0 : 0.f);
      float v1 = acc[mt][nt][1] + bv.y; hv[1] = (f16)(v1 > 0.f ? v1 : 0.f);
      float v2 = acc[mt][nt][2] + bv.z; hv[2] = (f16)(v2 > 0.f ? v2 : 0.f);
      float v3 = acc[mt][nt][3] + bv.w; hv[3] = (f16)(v3 > 0.f ? v3 : 0.f);
      const int row = mt * 16 + l16;
      *(f16x4*)&H[row * 512 + (((c0 >> 3) ^ l16) << 3) + (quad & 1) * 4] = hv;
    }
  }
}

// ---------------------------------------------------------------------------
// Barrier-free K-loop (round-8 proven). B: global->VGPR from FRAGMENT-LINEAR
// weights (coalesced 1KB dwordx4). A: via GetA (ds_read or global). BD/AD
// rings, counted waits, no __syncthreads inside.
// REGISTER REGIME (rounds 4-12, five failed experiments): occupancy buckets
// at total(arch+acc) 64/128/256 per wave. MT=4 at (512,2): ~184 total ->
// 2 waves/SIMD, NO spill (rounds 6/8 measured WRITE=17MB). Every attempt to
// move tile size (MT=8, MT=2) or launch bounds spilled 190MB-3GB scratch.
// DO NOT move tile size or launch bounds again.
// ---------------------------------------------------------------------------
template<int NC, int MT, int NT, int BD, int AD, bool AGLOB, bool SWAP,
         typename GetB, typename GetA>
__device__ __forceinline__ void kloop(GetB getB, GetA getA, f32x4 (&acc)[MT][NT])
{
  f16x8 bs[BD][NT];
  f16x8 as[AD][MT];
#pragma unroll
  for (int c = 0; c < BD - 1 && c < NC; c++)
#pragma unroll
    for (int nt = 0; nt < NT; nt++) bs[c][nt] = getB(c, nt);
#pragma unroll
  for (int c = 0; c < AD - 1 && c < NC; c++)
#pragma unroll
    for (int mt = 0; mt < MT; mt++) as[c][mt] = getA(c, mt);

  auto lp = [&](auto&& self, auto Cc) -> void {
    constexpr int C = decltype(Cc)::value;
    if constexpr (C < NC) {
      if constexpr (C + BD - 1 < NC) {
#pragma unroll
        for (int nt = 0; nt < NT; nt++) bs[(C + BD - 1) % BD][nt] = getB(C + BD - 1, nt);
      }
      if constexpr (C + AD - 1 < NC) {
#pragma unroll
        for (int mt = 0; mt < MT; mt++) as[(C + AD - 1) % AD][mt] = getA(C + AD - 1, mt);
      }
      constexpr int BOUT = (BD - 1) < (NC - 1 - C) ? (BD - 1) : (NC - 1 - C);
      constexpr int AOUT = (AD - 1) < (NC - 1 - C) ? (AD - 1) : (NC - 1 - C);
      if constexpr (AGLOB) waitcnt_t<0, 0>();       // A-globals share vmcnt
      else                 waitcnt_t<NT * BOUT, MT * AOUT>();
      __builtin_amdgcn_s_setprio(1);
#pragma unroll
      for (int mt = 0; mt < MT; mt++)
#pragma unroll
        for (int nt = 0; nt < NT; nt++)
          acc[mt][nt] = SWAP ? MFMA(bs[C % BD][nt], as[C % AD][mt], acc[mt][nt])
                             : MFMA(as[C % AD][mt], bs[C % BD][nt], acc[mt][nt]);
      __builtin_amdgcn_s_setprio(0);
      self(self, ic<C + 1>{});
    }
  };
  lp(lp, ic<0>{});
}

// one 512-col layer, 64 rows (MT=4), 8 waves each owning 64 cols.
// B fragment-linear: frag(c, cb, lane) at ((c*32 + cb)*64 + lane)*8 f16,
// cb = wave*4 + nt.
template<int K, bool AGLOB, typename GetA>
__device__ __forceinline__ void run_layer(
    const f16* __restrict__ Wt, const float* __restrict__ bias,
    f16* __restrict__ H, int wave, int lane, int quad, int l16, GetA getA)
{
  constexpr int NC = K / 32;
  const int wcb = wave * 64;
  const f16* bbase = Wt + (long)(wave * 4) * 512 + lane * 8;
  auto getB = [&](int c, int nt) -> f16x8 {
    return *(const f16x8*)(bbase + (long)(c * 32 + nt) * 512);
  };
  f32x4 acc[4][4];
#pragma unroll
  for (int i = 0; i < 4; i++)
#pragma unroll
    for (int j = 0; j < 4; j++) acc[i][j] = f32x4{0.f, 0.f, 0.f, 0.f};

  kloop<NC, 4, 4, 4, 2, AGLOB, true>(getB, getA, acc);  // swapped: row=l16, col=quad*4+r

  __syncthreads();                 // all H/X reads of this layer done
  storeH_fn<4>(H, acc, bias, wcb, quad, l16);
  __syncthreads();                 // H visible for next layer
}

// ---------------- fused 4-layer MLP, 64 rows/block, 512 thr, any level ------
// (round-8 proven structure; only change: out layer uses ALL 8 waves with an
//  UNEVEN col split — 5 col blocks = 3 + 2. Round 13's even 4x2 split missed
//  col block 4 entirely (cols 64-79, incl. the real col 64) -> absmax fail.)
// LDS: H[64][512] = 64KB. X[64][232] (internal l0 input) aliases H — safe:
// storeH(l0) writes H only after the barrier when all X reads are done.
__global__ __launch_bounds__(512, 2) void fused_mlp(
    const float* __restrict__ feats,
    const f16* __restrict__ w0t, const float* __restrict__ b0,
    const f16* __restrict__ w1t, const float* __restrict__ b1,
    const f16* __restrict__ w2t, const float* __restrict__ b2,
    const f16* __restrict__ wot, const float* __restrict__ bo,
    f16* __restrict__ tree, float* __restrict__ dOut, int lvl, int leaf)
{
  extern __shared__ f16 S[];
  f16* H = S;            // 32768 f16
  f16* X = S;            // [64][232] (internal l0 only; alias of H)

  const int tid  = threadIdx.x;
  const int wave = tid >> 6;
  const int lane = tid & 63;
  const int quad = lane >> 4;
  const int l16  = lane & 15;
  const long rowBase = (long)blockIdx.x * 64;

  if (!leaf) {
    // feats: 64 rows x 64, f32->f16, coalesced
    for (int i = tid; i < 4096; i += 512) {
      int r = i >> 6, cc = i & 63;
      long rg = rowBase + r;
      long bbr = rg >> lvl;
      long ii = rg - (bbr << lvl);
      long nn = (1L << lvl) - 1 + ii;
      X[r * 232 + cc] = (f16)feats[(bbr * N_INTN + nn) * 64 + cc];
    }
    // children: 64 rows x 132 f16 VERBATIM copy (66 u32/row, contiguous).
    // Junk cols (col65 of each child) land at k=129,195: weight rows there
    // are ZERO (hole repack + K bound), and tree col65 is zeroed by every
    // epilogue, so junk is finite -> 0*finite = 0.
    for (int i = tid; i < 4224; i += 512) {
      int r = i / 66, c = i - r * 66;
      long rg = rowBase + r;
      long bbr = rg >> lvl;
      long ii = rg - (bbr << lvl);
      long nn = (1L << lvl) - 1 + ii;
      const uint32_t* src = (const uint32_t*)(tree + (bbr * N_NODE + 2 * nn + 1) * TREE_STRIDE);
      *(uint32_t*)(X + r * 232 + 64 + 2 * c) = src[c];
    }
    // zero k=196..223 (read range ends at 223; avoid NaN*0)
    for (int i = tid; i < 1792; i += 512) {
      int r = i / 28, cc = i - r * 28;
      X[r * 232 + 196 + cc] = (f16)0.f;
    }
    __syncthreads();
  }

  // ---- layer 0 ----
  if (leaf) {
    auto gA = [&](int c, int mt) -> f16x8 {
      const float4* p = (const float4*)(feats + (rowBase + mt * 16 + l16) * 64 + c * 32 + quad * 8);
      float4 u0 = p[0], u1 = p[1];
      f16x8 a;
      a[0] = (f16)u0.x; a[1] = (f16)u0.y; a[2] = (f16)u0.z; a[3] = (f16)u0.w;
      a[4] = (f16)u1.x; a[5] = (f16)u1.y; a[6] = (f16)u1.z; a[7] = (f16)u1.w;
      return a;
    };
    run_layer<64, true>(w0t, b0, H, wave, lane, quad, l16, gA);
  } else {
    auto gA = [&](int c, int mt) -> f16x8 {
      int row = mt * 16 + l16;
      return *(const f16x8*)&X[row * 232 + c * 32 + quad * 8];  // max 223 < 232
    };
    run_layer<224, false>(w0t, b0, H, wave, lane, quad, l16, gA);
  }

  // ---- mid layers (A from H) ----
  auto getAH = [&](int c, int mt) -> f16x8 {
    int row = mt * 16 + l16;
    return *(const f16x8*)&H[row * 512 + ((((c * 4 + quad) ^ l16) << 3))];
  };
  run_layer<512, false>(w1t, b1, H, wave, lane, quad, l16, getAH);
  run_layer<512, false>(w2t, b2, H, wave, lane, quad, l16, getAH);

  // ---- out layer (512 -> 65, padded 80 cols, frag-linear NB=5), 8 waves:
  //      wave w: row-group g=w&3 (16 rows), col-group cp=w>>2:
  //        cp=0 -> col blocks {0,1,2} (NT=3), cp=1 -> {3,4} (NT=2).
  //      All 5 blocks covered (cols 0..79: value col 64 + pad col 65). ----
  {
    const int g  = wave & 3;
    const int cp = wave >> 2;
    const int orow = g * 16 + l16;
    auto gA = [&](int c, int mt) -> f16x8 {
      return *(const f16x8*)&H[orow * 512 + ((((c * 4 + quad) ^ l16) << 3))];
    };
    const long rgb = rowBase + g * 16 + quad * 4;

    auto doOut = [&](auto NTc, int cb0) {
      constexpr int NT = decltype(NTc)::value;
      const f16* obase = wot + (long)cb0 * 512 + lane * 8;
      auto gB = [&](int c, int nt) -> f16x8 {
        return *(const f16x8*)(obase + (long)(c * 5 + nt) * 512);
      };
      f32x4 oacc[1][NT];
#pragma unroll
      for (int i = 0; i < NT; i++) oacc[0][i] = f32x4{0.f, 0.f, 0.f, 0.f};

      kloop<16, 1, NT, 3, 2, false, false>(gB, gA, oacc);  // normal: row=quad*4+r

      f16* tptr[4];
#pragma unroll
      for (int r = 0; r < 4; r++) {
        long rg = rgb + r;
        long b2_ = rg >> lvl;
        long ii  = rg - (b2_ << lvl);
        long node = (1L << lvl) - 1 + ii;
        tptr[r] = tree + (b2_ * N_NODE + node) * TREE_STRIDE;
      }
#pragma unroll
      for (int nt = 0; nt < NT; nt++)
#pragma unroll
        for (int r = 0; r < 4; r++) {
          int col = (cb0 + nt) * 16 + l16;
          if (col < OUT_DIM) {
            float v = oacc[0][nt][r] + bo[col];
            tptr[r][col] = (f16)v;
            if (lvl == 0 && col == 0) dOut[rgb + r] = v;   // lvl 0: row = batch idx
          } else if (col == OUT_DIM) {
            tptr[r][col] = (f16)0.f;  // zero pad col for child verbatim-copies
          }
        }
    };
    if (cp == 0) doOut(ic<3>{}, 0);
    else         doOut(ic<2>{}, 3);
  }
}

// ---------------- weight repack: transpose+cast to FRAGMENT-LINEAR ----------
// elem e of a segment: j=e&7, lane=(e>>3)&63, q=e>>9, cb=q%NB, c=q/NB;
// stores W[k= c*32+(lane>>4)*8+j][col= cb*16+(lane&15)] (0-padded).
// hole: logical row `hole` is a ZERO row and source rows shift by 1 above it
// (maps the verbatim child-copy junk slots k=129/195 to zero weights).
struct WSeg { const float* W; f16* Wt; int K, N, NB, hole, start; };
struct WPack { WSeg s[8]; int total; };

__global__ void wcast_all(WPack p) {
  int idx = blockIdx.x * 256 + threadIdx.x;
  if (idx >= p.total) return;
  int si = 0;
#pragma unroll
  for (int i = 1; i < 8; i++) if (idx >= p.s[i].start) si = i;
  WSeg sg = p.s[si];
  int e = idx - sg.start;
  int j = e & 7, lane = (e >> 3) & 63, q = e >> 9;
  int cb = q % sg.NB, c = q / sg.NB;
  int col = cb * 16 + (lane & 15);
  int k = c * 32 + (lane >> 4) * 8 + j;
  int srck = (k < sg.hole) ? k : k - 1;
  float v = (k != sg.hole && srck < sg.K && col < sg.N)
                ? sg.W[(long)srck * sg.N + col] : 0.f;
  sg.Wt[e] = (f16)v;
}

// ---------------- host orchestration ----------------
extern "C" void kernel_launch(void* const* d_in, const int* in_sizes, int n_in,
                              void* d_out, int out_size, void* d_ws, size_t ws_size,
                              hipStream_t stream) {
  const float* leaf_feats     = (const float*)d_in[0];
  const float* internal_feats = (const float*)d_in[1];
  const float* lw0 = (const float*)d_in[2];
  const float* lb0 = (const float*)d_in[3];
  const float* lw1 = (const float*)d_in[4];
  const float* lb1 = (const float*)d_in[5];
  const float* lw2 = (const float*)d_in[6];
  const float* lb2 = (const float*)d_in[7];
  const float* lwo = (const float*)d_in[8];
  const float* lbo = (const float*)d_in[9];
  const float* iw0 = (const float*)d_in[10];
  const float* ib0 = (const float*)d_in[11];
  const float* iw1 = (const float*)d_in[12];
  const float* ib1 = (const float*)d_in[13];
  const float* iw2 = (const float*)d_in[14];
  const float* ib2 = (const float*)d_in[15];
  const float* iwo = (const float*)d_in[16];
  const float* ibo = (const float*)d_in[17];
  float* dOut = (float*)d_out;

  char* ws = (char*)d_ws;
  size_t off = 0;
  auto alloc = [&](size_t bytes) -> void* {
    void* p = ws + off;
    off += (bytes + 255) & ~(size_t)255;
    return p;
  };

  f16* lw0t = (f16*)alloc((size_t)64  * 512 * 2);
  f16* lw1t = (f16*)alloc((size_t)512 * 512 * 2);
  f16* lw2t = (f16*)alloc((size_t)512 * 512 * 2);
  f16* lwot = (f16*)alloc((size_t)512 * 80  * 2);
  f16* iw0t = (f16*)alloc((size_t)224 * 512 * 2);
  f16* iw1t = (f16*)alloc((size_t)512 * 512 * 2);
  f16* iw2t = (f16*)alloc((size_t)512 * 512 * 2);
  f16* iwot = (f16*)alloc((size_t)512 * 80  * 2);
  f16* tree = (f16*)alloc((size_t)256 * N_NODE * TREE_STRIDE * 2);

  const int NOHOLE = 1 << 30;
  WPack p;
  int cum = 0;
  auto seg = [&](int i, const float* W, f16* Wt, int K, int N, int Kpad, int NB, int hole) {
    p.s[i] = {W, Wt, K, N, NB, hole, cum};
    cum += Kpad * NB * 16;
  };
  seg(0, lw0, lw0t, 64, 512, 64, 32, NOHOLE);
  seg(1, lw1, lw1t, 512, 512, 512, 32, NOHOLE);
  seg(2, lw2, lw2t, 512, 512, 512, 32, NOHOLE);
  seg(3, lwo, lwot, 512, 65, 512, 5, NOHOLE);
  seg(4, iw0, iw0t, 194, 512, 224, 32, 129);   // hole at k=129 (left child pad)
  seg(5, iw1, iw1t, 512, 512, 512, 32, NOHOLE);
  seg(6, iw2, iw2t, 512, 512, 512, 32, NOHOLE);
  seg(7, iwo, iwot, 512, 65, 512, 5, NOHOLE);
  p.total = cum;
  wcast_all<<<dim3((cum + 255) / 256), dim3(256), 0, stream>>>(p);

  static bool attrSet = false;
  if (!attrSet) {
    hipFuncSetAttribute(reinterpret_cast<const void*>(fused_mlp),
                        hipFuncAttributeMaxDynamicSharedMemorySize, 65536);
    attrSet = true;
  }

  const size_t shmem = 65536;   // H 64KB (X aliased)

  // leaf pass: 131072 rows -> nodes 511..1022
  fused_mlp<<<dim3(2048), dim3(512), shmem, stream>>>(
      leaf_feats, lw0t, lb0, lw1t, lb1, lw2t, lb2, lwot, lbo, tree, dOut, 9, 1);

  // internal levels 8..0 (grid = rows/64 = 4<<l; weights stay L2-hot)
  for (int l = 8; l >= 0; l--) {
    fused_mlp<<<dim3(4u << l), dim3(512), shmem, stream>>>(
        internal_feats, iw0t, ib0, iw1t, ib1, iw2t, ib2, iwot, ibo, tree, dOut, l, 0);
  }

  (void)in_sizes; (void)n_in; (void)out_size; (void)ws_size;
}

// Round 16
// 631.876 us; speedup vs baseline: 1.6529x; 1.0018x over previous
//
#include <hip/hip_runtime.h>
#include <cstdint>
#include <cstddef>
#include <type_traits>

// ---------------- problem constants ----------------
#define OUT_DIM    65
#define TREE_STRIDE 66
#define N_NODE     1023
#define N_INTN     511

typedef _Float16 f16;
typedef _Float16 f16x8 __attribute__((ext_vector_type(8)));
typedef _Float16 f16x4 __attribute__((ext_vector_type(4)));
typedef float    f32x4 __attribute__((ext_vector_type(4)));

template<int V> using ic = std::integral_constant<int, V>;

#define MFMA(a, b, c) __builtin_amdgcn_mfma_f32_16x16x32_f16((a), (b), (c), 0, 0, 0)

// counted wait, compile-time immediates; "memory" clobber pins load scheduling.
// Correctness never relies on these (compiler emits its own waits before each
// use of a loaded value); they only ADD earlier/looser waits for scheduling.
// NOTE (round 15 lesson): do NOT add dangling inline-asm loads ("touch"
// prefetch) — the compiler reuses the dest VGPR of an asm load it believes
// is complete, and the late-landing load corrupts it -> GPU fault.
template<int VM, int LG>
__device__ __forceinline__ void waitcnt_t() {
  asm volatile("s_waitcnt vmcnt(%0) lgkmcnt(%1)" :: "n"(VM), "n"(LG) : "memory");
}

// H swizzle: elem(row,k) at row*512 + (((k>>3) ^ (row&15))<<3) + (k&7)
template<int MT>
__device__ __forceinline__ void storeH_fn(f16* __restrict__ H, f32x4 (&acc)[MT][4],
                                          const float* __restrict__ bias,
                                          int wcb, int quad, int l16) {
#pragma unroll
  for (int mt = 0; mt < MT; mt++) {
#pragma unroll
    for (int nt = 0; nt < 4; nt++) {
      const int c0 = wcb + nt * 16 + quad * 4;
      const float4 bv = *(const float4*)(bias + c0);
      f16x4 hv;
      float v0 = acc[mt][nt][0] + bv.x; hv[0] = (f16)(v0 > 0.f ? v0 : 0.f);
      float v1 = acc[mt][nt][1] + bv.y; hv[1] = (f16)(v1 > 0.f ? v1 : 0.f);
      float v2 = acc[mt][nt][2] + bv.z; hv[2] = (f16)(v2 > 0.f ? v2 : 0.f);
      float v3 = acc[mt][nt][3] + bv.w; hv[3] = (f16)(v3 > 0.f ? v3 : 0.f);
      const int row = mt * 16 + l16;
      *(f16x4*)&H[row * 512 + (((c0 >> 3) ^ l16) << 3) + (quad & 1) * 4] = hv;
    }
  }
}

// ---------------------------------------------------------------------------
// Barrier-free K-loop (round-8 proven). B: global->VGPR from FRAGMENT-LINEAR
// weights (coalesced 1KB dwordx4). A: via GetA (ds_read or global). BD/AD
// rings, counted waits, no __syncthreads inside.
// REGISTER REGIME (rounds 4-12, five failed experiments): occupancy buckets
// at total(arch+acc) 64/128/256 per wave. MT=4 at (512,2): ~184 total ->
// 2 waves/SIMD, NO spill (rounds 6/8 measured WRITE=17MB). Every attempt to
// move tile size (MT=8, MT=2) or launch bounds spilled 190MB-3GB scratch.
// DO NOT move tile size or launch bounds again.
// ---------------------------------------------------------------------------
template<int NC, int MT, int NT, int BD, int AD, bool AGLOB, bool SWAP,
         typename GetB, typename GetA>
__device__ __forceinline__ void kloop(GetB getB, GetA getA, f32x4 (&acc)[MT][NT])
{
  f16x8 bs[BD][NT];
  f16x8 as[AD][MT];
#pragma unroll
  for (int c = 0; c < BD - 1 && c < NC; c++)
#pragma unroll
    for (int nt = 0; nt < NT; nt++) bs[c][nt] = getB(c, nt);
#pragma unroll
  for (int c = 0; c < AD - 1 && c < NC; c++)
#pragma unroll
    for (int mt = 0; mt < MT; mt++) as[c][mt] = getA(c, mt);

  auto lp = [&](auto&& self, auto Cc) -> void {
    constexpr int C = decltype(Cc)::value;
    if constexpr (C < NC) {
      if constexpr (C + BD - 1 < NC) {
#pragma unroll
        for (int nt = 0; nt < NT; nt++) bs[(C + BD - 1) % BD][nt] = getB(C + BD - 1, nt);
      }
      if constexpr (C + AD - 1 < NC) {
#pragma unroll
        for (int mt = 0; mt < MT; mt++) as[(C + AD - 1) % AD][mt] = getA(C + AD - 1, mt);
      }
      constexpr int BOUT = (BD - 1) < (NC - 1 - C) ? (BD - 1) : (NC - 1 - C);
      constexpr int AOUT = (AD - 1) < (NC - 1 - C) ? (AD - 1) : (NC - 1 - C);
      if constexpr (AGLOB) waitcnt_t<0, 0>();       // A-globals share vmcnt
      else                 waitcnt_t<NT * BOUT, MT * AOUT>();
      __builtin_amdgcn_s_setprio(1);
#pragma unroll
      for (int mt = 0; mt < MT; mt++)
#pragma unroll
        for (int nt = 0; nt < NT; nt++)
          acc[mt][nt] = SWAP ? MFMA(bs[C % BD][nt], as[C % AD][mt], acc[mt][nt])
                             : MFMA(as[C % AD][mt], bs[C % BD][nt], acc[mt][nt]);
      __builtin_amdgcn_s_setprio(0);
      self(self, ic<C + 1>{});
    }
  };
  lp(lp, ic<0>{});
}

// one 512-col layer, 64 rows (MT=4), 8 waves each owning 64 cols.
// B fragment-linear: frag(c, cb, lane) at ((c*32 + cb)*64 + lane)*8 f16,
// cb = wave*4 + nt.
template<int K, bool AGLOB, typename GetA>
__device__ __forceinline__ void run_layer(
    const f16* __restrict__ Wt, const float* __restrict__ bias,
    f16* __restrict__ H, int wave, int lane, int quad, int l16, GetA getA)
{
  constexpr int NC = K / 32;
  const int wcb = wave * 64;
  const f16* bbase = Wt + (long)(wave * 4) * 512 + lane * 8;
  auto getB = [&](int c, int nt) -> f16x8 {
    return *(const f16x8*)(bbase + (long)(c * 32 + nt) * 512);
  };
  f32x4 acc[4][4];
#pragma unroll
  for (int i = 0; i < 4; i++)
#pragma unroll
    for (int j = 0; j < 4; j++) acc[i][j] = f32x4{0.f, 0.f, 0.f, 0.f};

  kloop<NC, 4, 4, 4, 2, AGLOB, true>(getB, getA, acc);  // swapped: row=l16, col=quad*4+r

  __syncthreads();                 // all H/X reads of this layer done
  storeH_fn<4>(H, acc, bias, wcb, quad, l16);
  __syncthreads();                 // H visible for next layer
}

// ---------------- fused 4-layer MLP, 64 rows/block, 512 thr, any level ------
// Round-8 proven structure. Out layer: leaf -> 4-wave NT=5 (r8 path; the
// 8-wave split measured +9us on leaf in r14); internal -> 8-wave uneven
// split (3+2 col blocks; r13's even 4x2 split MISSED col block 4 -> fail).
// LDS: H[64][512] = 64KB. X[64][232] (internal l0 input) aliases H — safe:
// storeH(l0) writes H only after the barrier when all X reads are done.
__global__ __launch_bounds__(512, 2) void fused_mlp(
    const float* __restrict__ feats,
    const f16* __restrict__ w0t, const float* __restrict__ b0,
    const f16* __restrict__ w1t, const float* __restrict__ b1,
    const f16* __restrict__ w2t, const float* __restrict__ b2,
    const f16* __restrict__ wot, const float* __restrict__ bo,
    f16* __restrict__ tree, float* __restrict__ dOut, int lvl, int leaf)
{
  extern __shared__ f16 S[];
  f16* H = S;            // 32768 f16
  f16* X = S;            // [64][232] (internal l0 only; alias of H)

  const int tid  = threadIdx.x;
  const int wave = tid >> 6;
  const int lane = tid & 63;
  const int quad = lane >> 4;
  const int l16  = lane & 15;
  const long rowBase = (long)blockIdx.x * 64;

  if (!leaf) {
    // feats: 64 rows x 64, f32->f16, coalesced
    for (int i = tid; i < 4096; i += 512) {
      int r = i >> 6, cc = i & 63;
      long rg = rowBase + r;
      long bbr = rg >> lvl;
      long ii = rg - (bbr << lvl);
      long nn = (1L << lvl) - 1 + ii;
      X[r * 232 + cc] = (f16)feats[(bbr * N_INTN + nn) * 64 + cc];
    }
    // children: 64 rows x 132 f16 VERBATIM copy (66 u32/row, contiguous).
    // Junk cols (col65 of each child) land at k=129,195: weight rows there
    // are ZERO (hole repack + K bound), and tree col65 is zeroed by every
    // epilogue, so junk is finite -> 0*finite = 0.
    for (int i = tid; i < 4224; i += 512) {
      int r = i / 66, c = i - r * 66;
      long rg = rowBase + r;
      long bbr = rg >> lvl;
      long ii = rg - (bbr << lvl);
      long nn = (1L << lvl) - 1 + ii;
      const uint32_t* src = (const uint32_t*)(tree + (bbr * N_NODE + 2 * nn + 1) * TREE_STRIDE);
      *(uint32_t*)(X + r * 232 + 64 + 2 * c) = src[c];
    }
    // zero k=196..223 (read range ends at 223; avoid NaN*0)
    for (int i = tid; i < 1792; i += 512) {
      int r = i / 28, cc = i - r * 28;
      X[r * 232 + 196 + cc] = (f16)0.f;
    }
    __syncthreads();
  }

  // ---- layer 0 ----
  if (leaf) {
    auto gA = [&](int c, int mt) -> f16x8 {
      const float4* p = (const float4*)(feats + (rowBase + mt * 16 + l16) * 64 + c * 32 + quad * 8);
      float4 u0 = p[0], u1 = p[1];
      f16x8 a;
      a[0] = (f16)u0.x; a[1] = (f16)u0.y; a[2] = (f16)u0.z; a[3] = (f16)u0.w;
      a[4] = (f16)u1.x; a[5] = (f16)u1.y; a[6] = (f16)u1.z; a[7] = (f16)u1.w;
      return a;
    };
    run_layer<64, true>(w0t, b0, H, wave, lane, quad, l16, gA);
  } else {
    auto gA = [&](int c, int mt) -> f16x8 {
      int row = mt * 16 + l16;
      return *(const f16x8*)&X[row * 232 + c * 32 + quad * 8];  // max 223 < 232
    };
    run_layer<224, false>(w0t, b0, H, wave, lane, quad, l16, gA);
  }

  // ---- mid layers (A from H) ----
  auto getAH = [&](int c, int mt) -> f16x8 {
    int row = mt * 16 + l16;
    return *(const f16x8*)&H[row * 512 + ((((c * 4 + quad) ^ l16) << 3))];
  };
  run_layer<512, false>(w1t, b1, H, wave, lane, quad, l16, getAH);
  run_layer<512, false>(w2t, b2, H, wave, lane, quad, l16, getAH);

  // ---- out layer (512 -> 65, padded 80 cols, frag-linear NB=5) ----
  {
    auto doOut = [&](auto NTc, int cb0, int g) {
      constexpr int NT = decltype(NTc)::value;
      const int orow = g * 16 + l16;
      auto gA = [&](int c, int mt) -> f16x8 {
        return *(const f16x8*)&H[orow * 512 + ((((c * 4 + quad) ^ l16) << 3))];
      };
      const long rgb = rowBase + g * 16 + quad * 4;
      const f16* obase = wot + (long)cb0 * 512 + lane * 8;
      auto gB = [&](int c, int nt) -> f16x8 {
        return *(const f16x8*)(obase + (long)(c * 5 + nt) * 512);
      };
      f32x4 oacc[1][NT];
#pragma unroll
      for (int i = 0; i < NT; i++) oacc[0][i] = f32x4{0.f, 0.f, 0.f, 0.f};

      kloop<16, 1, NT, 3, 2, false, false>(gB, gA, oacc);  // normal: row=quad*4+r

      f16* tptr[4];
#pragma unroll
      for (int r = 0; r < 4; r++) {
        long rg = rgb + r;
        long b2_ = rg >> lvl;
        long ii  = rg - (b2_ << lvl);
        long node = (1L << lvl) - 1 + ii;
        tptr[r] = tree + (b2_ * N_NODE + node) * TREE_STRIDE;
      }
#pragma unroll
      for (int nt = 0; nt < NT; nt++)
#pragma unroll
        for (int r = 0; r < 4; r++) {
          int col = (cb0 + nt) * 16 + l16;
          if (col < OUT_DIM) {
            float v = oacc[0][nt][r] + bo[col];
            tptr[r][col] = (f16)v;
            if (lvl == 0 && col == 0) dOut[rgb + r] = v;   // lvl 0: row = batch idx
          } else if (col == OUT_DIM) {
            tptr[r][col] = (f16)0.f;  // zero pad col for child verbatim-copies
          }
        }
    };
    if (leaf) {
      if (wave < 4) doOut(ic<5>{}, 0, wave);         // r8 path: 4 waves x NT=5
    } else {
      const int g = wave & 3, cp = wave >> 2;        // 8 waves: 3+2 col split
      if (cp == 0) doOut(ic<3>{}, 0, g);
      else         doOut(ic<2>{}, 3, g);
    }
  }
}

// ---------------- weight repack: transpose+cast to FRAGMENT-LINEAR ----------
// elem e of a segment: j=e&7, lane=(e>>3)&63, q=e>>9, cb=q%NB, c=q/NB;
// stores W[k= c*32+(lane>>4)*8+j][col= cb*16+(lane&15)] (0-padded).
// hole: logical row `hole` is a ZERO row and source rows shift by 1 above it
// (maps the verbatim child-copy junk slots k=129/195 to zero weights).
struct WSeg { const float* W; f16* Wt; int K, N, NB, hole, start; };
struct WPack { WSeg s[8]; int total; };

__global__ void wcast_all(WPack p) {
  int idx = blockIdx.x * 256 + threadIdx.x;
  if (idx >= p.total) return;
  int si = 0;
#pragma unroll
  for (int i = 1; i < 8; i++) if (idx >= p.s[i].start) si = i;
  WSeg sg = p.s[si];
  int e = idx - sg.start;
  int j = e & 7, lane = (e >> 3) & 63, q = e >> 9;
  int cb = q % sg.NB, c = q / sg.NB;
  int col = cb * 16 + (lane & 15);
  int k = c * 32 + (lane >> 4) * 8 + j;
  int srck = (k < sg.hole) ? k : k - 1;
  float v = (k != sg.hole && srck < sg.K && col < sg.N)
                ? sg.W[(long)srck * sg.N + col] : 0.f;
  sg.Wt[e] = (f16)v;
}

// ---------------- host orchestration ----------------
extern "C" void kernel_launch(void* const* d_in, const int* in_sizes, int n_in,
                              void* d_out, int out_size, void* d_ws, size_t ws_size,
                              hipStream_t stream) {
  const float* leaf_feats     = (const float*)d_in[0];
  const float* internal_feats = (const float*)d_in[1];
  const float* lw0 = (const float*)d_in[2];
  const float* lb0 = (const float*)d_in[3];
  const float* lw1 = (const float*)d_in[4];
  const float* lb1 = (const float*)d_in[5];
  const float* lw2 = (const float*)d_in[6];
  const float* lb2 = (const float*)d_in[7];
  const float* lwo = (const float*)d_in[8];
  const float* lbo = (const float*)d_in[9];
  const float* iw0 = (const float*)d_in[10];
  const float* ib0 = (const float*)d_in[11];
  const float* iw1 = (const float*)d_in[12];
  const float* ib1 = (const float*)d_in[13];
  const float* iw2 = (const float*)d_in[14];
  const float* ib2 = (const float*)d_in[15];
  const float* iwo = (const float*)d_in[16];
  const float* ibo = (const float*)d_in[17];
  float* dOut = (float*)d_out;

  char* ws = (char*)d_ws;
  size_t off = 0;
  auto alloc = [&](size_t bytes) -> void* {
    void* p = ws + off;
    off += (bytes + 255) & ~(size_t)255;
    return p;
  };

  f16* lw0t = (f16*)alloc((size_t)64  * 512 * 2);
  f16* lw1t = (f16*)alloc((size_t)512 * 512 * 2);
  f16* lw2t = (f16*)alloc((size_t)512 * 512 * 2);
  f16* lwot = (f16*)alloc((size_t)512 * 80  * 2);
  f16* iw0t = (f16*)alloc((size_t)224 * 512 * 2);
  f16* iw1t = (f16*)alloc((size_t)512 * 512 * 2);
  f16* iw2t = (f16*)alloc((size_t)512 * 512 * 2);
  f16* iwot = (f16*)alloc((size_t)512 * 80  * 2);
  f16* tree = (f16*)alloc((size_t)256 * N_NODE * TREE_STRIDE * 2);

  const int NOHOLE = 1 << 30;
  WPack p;
  int cum = 0;
  auto seg = [&](int i, const float* W, f16* Wt, int K, int N, int Kpad, int NB, int hole) {
    p.s[i] = {W, Wt, K, N, NB, hole, cum};
    cum += Kpad * NB * 16;
  };
  seg(0, lw0, lw0t, 64, 512, 64, 32, NOHOLE);
  seg(1, lw1, lw1t, 512, 512, 512, 32, NOHOLE);
  seg(2, lw2, lw2t, 512, 512, 512, 32, NOHOLE);
  seg(3, lwo, lwot, 512, 65, 512, 5, NOHOLE);
  seg(4, iw0, iw0t, 194, 512, 224, 32, 129);   // hole at k=129 (left child pad)
  seg(5, iw1, iw1t, 512, 512, 512, 32, NOHOLE);
  seg(6, iw2, iw2t, 512, 512, 512, 32, NOHOLE);
  seg(7, iwo, iwot, 512, 65, 512, 5, NOHOLE);
  p.total = cum;
  wcast_all<<<dim3((cum + 255) / 256), dim3(256), 0, stream>>>(p);

  static bool attrSet = false;
  if (!attrSet) {
    hipFuncSetAttribute(reinterpret_cast<const void*>(fused_mlp),
                        hipFuncAttributeMaxDynamicSharedMemorySize, 65536);
    attrSet = true;
  }

  const size_t shmem = 65536;   // H 64KB (X aliased)

  // leaf pass: 131072 rows -> nodes 511..1022
  fused_mlp<<<dim3(2048), dim3(512), shmem, stream>>>(
      leaf_feats, lw0t, lb0, lw1t, lb1, lw2t, lb2, lwot, lbo, tree, dOut, 9, 1);

  // internal levels 8..0 (grid = rows/64 = 4<<l; weights stay L2-hot)
  for (int l = 8; l >= 0; l--) {
    fused_mlp<<<dim3(4u << l), dim3(512), shmem, stream>>>(
        internal_feats, iw0t, ib0, iw1t, ib1, iw2t, ib2, iwot, ibo, tree, dOut, l, 0);
  }

  (void)in_sizes; (void)n_in; (void)out_size; (void)ws_size;
}